// Round 11
// baseline (317.892 us; speedup 1.0000x reference)
//
#include <hip/hip_runtime.h>
#include <hip/hip_fp16.h>
#include <cstdint>
#include <cstddef>

#define NN 100000
#define NE 1600000
#define D 128
#define NBK 782            // ceil(NN / 128) row-buckets for gemm grid
#define SLOTS 64           // col slots per node; Poisson(16) -> P(deg>64) ~ 1e-22

typedef _Float16 half8 __attribute__((ext_vector_type(8)));
typedef _Float16 half4v __attribute__((ext_vector_type(4)));
typedef float f32x4 __attribute__((ext_vector_type(4)));

// ---------------- workspace layout (bytes) ----------------
// cnt  : NN u32       @ 0          (  400,000)  memset 0; ends as in-degree
// dinv : NN f32       @ 400,000    (  400,000)  written by gemm1 prologue
// z'   : NN*2 f32     @ 800,000    (  800,000)  dinv * (relu(agg+b1)@W2)
// Wt   : 128*128 f16  @ 1,600,000  (   32,768)  fp16 W1^T (scat_k blocks 0..63)
// col  : NN*64 u32    @ 1,638,400  (25,600,000) slotted: node i owns [i*64,i*64+64)
// h'   : NN*128 f16   @ 27,238,400 (25,600,000) dinv * (x@W1)
// total 52.8 MB (ws = 256 MiB). No buffer overlaps -> no cross-kernel races
// (R8 lesson: overlap legal under a kernel-boundary barrier races when fused).
// col slots >= cnt[i] hold garbage; always masked by uniform (k<degc) selects.

// SCAT: single-pass direct CSR build. One global atomicAdd reserves the slot
// AND accumulates the degree; col[dst*64+pos] = src. Replaces the R5-R9
// two-pass counting sort (LDS hist + reserve + part write + part read +
// LDS count/scan + regroup ~= 5 ops/edge, ~40us) with 2 ops/edge, one pass.
// Blocks 0..63 also emit Wt[n][k] = fp16 W1[k][n] (fused transpose+cast).
__launch_bounds__(256)
__global__ void scat_k(const int* __restrict__ ei, unsigned* __restrict__ cnt,
                       unsigned* __restrict__ col,
                       const float* __restrict__ W, _Float16* __restrict__ Wt) {
    int b = blockIdx.x, tid = threadIdx.x;
    if (b < 64) {  // fused Wt transpose+cast (16384 elems over 64 blocks)
        int idx = b * 256 + tid;
        int n = idx >> 7, kk = idx & 127;
        Wt[idx] = (_Float16)W[kk * 128 + n];
    }
    int i4 = (b * 256 + tid) * 4;
    if (i4 >= NE) return;  // NE%4==0 -> full int4 in bounds
    int4 s4 = *(const int4*)(ei + i4);
    int4 d4 = *(const int4*)(ei + NE + i4);
    unsigned k, pos;
    k = (unsigned)d4.x; pos = atomicAdd(&cnt[k], 1u);
    if (pos < SLOTS) col[(size_t)k * SLOTS + pos] = (unsigned)s4.x;
    k = (unsigned)d4.y; pos = atomicAdd(&cnt[k], 1u);
    if (pos < SLOTS) col[(size_t)k * SLOTS + pos] = (unsigned)s4.y;
    k = (unsigned)d4.z; pos = atomicAdd(&cnt[k], 1u);
    if (pos < SLOTS) col[(size_t)k * SLOTS + pos] = (unsigned)s4.z;
    k = (unsigned)d4.w; pos = atomicAdd(&cnt[k], 1u);
    if (pos < SLOTS) col[(size_t)k * SLOTS + pos] = (unsigned)s4.w;
}

// h' = dinv ⊙ (x @ W1), fp16 out, MFMA 16x16x32 f16. 128 rows/block, 4 waves;
// wave w covers rows w*32..w*32+31 (2 row-tiles) × all 8 col-tiles -> B-frag
// reused across 2 MFMAs. Prologue computes dinv = rsqrt(cnt+1) for its rows
// (stores for agg kernels, keeps LDS copy for the epilogue scale).
// LDS: wt 34.8K + xs 18.4K + dinvs 0.5K = 53.8K -> 3 blocks/CU.
// Verified layouts: A[m=lane&15][k=(lane>>4)*8+j], B[k][n=lane&15],
//                   C/D col=lane&15 row=(lane>>4)*4+reg.
__launch_bounds__(256)
__global__ void gemm1_k(const float* __restrict__ x, const _Float16* __restrict__ Wt,
                        const unsigned* __restrict__ cnt, float* __restrict__ dinv,
                        _Float16* __restrict__ h) {
    __shared__ __align__(16) _Float16 wt[128 * 136];  // B: wt[n][k]; reused as epilogue buffer
    __shared__ __align__(16) _Float16 xs[128 * 72];   // A: xs[row][k within 64-half]
    __shared__ float dinvs[128];
    int tid = threadIdx.x;
    int rb = blockIdx.x * 128;
    int w = tid >> 6, lane = tid & 63;
    int m = lane & 15, q4 = lane >> 4;

    // stage Wt: 2048 half8 chunks, coalesced global, conflict-free LDS
#pragma unroll
    for (int q = 0; q < 8; q++) {
        int idx = q * 256 + tid;
        int n = idx >> 4, k8 = (idx & 15) * 8;
        *(half8*)(&wt[n * 136 + k8]) = *(const half8*)(Wt + n * 128 + k8);
    }
    // dinv for this block's rows (cnt -> rsqrt), global store + LDS copy
    if (tid < 128) {
        int gr = rb + tid;
        unsigned c = (gr < NN) ? cnt[gr] : 0u;
        float dv = rsqrtf((float)(c + 1u));
        dinvs[tid] = dv;
        if (gr < NN) dinv[gr] = dv;
    }

    f32x4 acc[2][8];
#pragma unroll
    for (int rt = 0; rt < 2; rt++)
#pragma unroll
        for (int nt = 0; nt < 8; nt++) acc[rt][nt] = (f32x4){0.f, 0.f, 0.f, 0.f};

    for (int ks = 0; ks <= 64; ks += 64) {
        if (ks) __syncthreads();  // previous xs fully consumed
        // stage x rows [rb, rb+128) cols [ks, ks+64), fp32 -> fp16
#pragma unroll
        for (int q = 0; q < 8; q++) {
            int idx = q * 256 + tid;        // 0..2047
            int row = idx >> 4;
            int c4 = (idx & 15) * 4;
            int gr = rb + row;
            float4 v = (gr < NN) ? *(const float4*)(x + (size_t)gr * 128 + ks + c4)
                                 : make_float4(0, 0, 0, 0);
            half4v hv = { (_Float16)v.x, (_Float16)v.y, (_Float16)v.z, (_Float16)v.w };
            *(half4v*)(&xs[row * 72 + c4]) = hv;
        }
        __syncthreads();

#pragma unroll
        for (int kc = 0; kc < 2; kc++) {
            half8 a0 = *(const half8*)(&xs[(w * 32 + m) * 72 + kc * 32 + q4 * 8]);
            half8 a1 = *(const half8*)(&xs[(w * 32 + 16 + m) * 72 + kc * 32 + q4 * 8]);
#pragma unroll
            for (int nt = 0; nt < 8; nt++) {
                half8 bf = *(const half8*)(&wt[(nt * 16 + m) * 136 + ks + kc * 32 + q4 * 8]);
                acc[0][nt] = __builtin_amdgcn_mfma_f32_16x16x32_f16(a0, bf, acc[0][nt], 0, 0, 0);
                acc[1][nt] = __builtin_amdgcn_mfma_f32_16x16x32_f16(a1, bf, acc[1][nt], 0, 0, 0);
            }
        }
    }

    // epilogue: scale by dinv (LDS), fp16, stage in wt (dead), coalesced store
    float dv[2][4];
#pragma unroll
    for (int rt = 0; rt < 2; rt++)
#pragma unroll
        for (int r = 0; r < 4; r++)
            dv[rt][r] = dinvs[w * 32 + rt * 16 + q4 * 4 + r];
    __syncthreads();  // all wt reads done
#pragma unroll
    for (int rt = 0; rt < 2; rt++)
#pragma unroll
        for (int nt = 0; nt < 8; nt++)
#pragma unroll
            for (int r = 0; r < 4; r++)
                wt[(w * 32 + rt * 16 + q4 * 4 + r) * 136 + nt * 16 + m] =
                    (_Float16)(acc[rt][nt][r] * dv[rt][r]);
    __syncthreads();
#pragma unroll
    for (int q = 0; q < 8; q++) {
        int idx = q * 256 + tid;
        int row = idx >> 4;
        int c8 = (idx & 15) * 8;
        int gr = rb + row;
        if (gr < NN)
            *(half8*)(h + (size_t)gr * 128 + c8) = *(const half8*)(&wt[row * 136 + c8]);
    }
}

// Layer-1 aggregation of prescaled h' + bias/ReLU + 128x2 W2 projection.
// One wave per node; lane holds half2 (4B chunk; 64 lanes = full 256B row).
// Measured at the fill-path roofline (58.9us vs 193MB/3.37TB/s = 57us).
// Slotted col: node i's edges at [i*64, i*64+deg) -> the col window is ONE
// always-in-bounds load col[i*64+lane]; row ids via readlane -> SGPR gather
// addresses; full 16-gather rounds, padding slots gather row i (hot),
// corrected exactly by f = 1 + degc - 16*ceil(degc/16). fp32 accumulate.
__launch_bounds__(256)
__global__ void agg1_k(const _Float16* __restrict__ h, const unsigned* __restrict__ cnt,
                       const unsigned* __restrict__ col, const float* __restrict__ dinv,
                       const float* __restrict__ b1, const float* __restrict__ W2,
                       float* __restrict__ z) {
    int i = (blockIdx.x * 256 + threadIdx.x) >> 6;
    int lane = threadIdx.x & 63;
    if (i >= NN) return;
    unsigned si = __builtin_amdgcn_readfirstlane((unsigned)i);  // force SGPR

    const __half2* hb = (const __half2*)h;
    int deg = (int)__builtin_amdgcn_readfirstlane(cnt[si]);

    // col window: one per-lane load covers the node's 64 slots; slots >= deg
    // hold garbage, masked by wave-uniform (k<degc) selects.
    unsigned cv = col[(size_t)si * SLOTS + (unsigned)lane];

    int degc = deg > 64 ? 64 : deg;       // deg>64: P ~ 1e-22, excess dropped
    int R = (degc + 15) >> 4;             // full 16-rounds incl. padding
    float2 sv = __half22float2(hb[(size_t)si * 64u + lane]);
    float f = (float)(1 + degc - 16 * R); // corrects padding reads of row si
    float ax = f * sv.x, ay = f * sv.y;

#define ROUND16(r)                                                           \
    {                                                                        \
        float2 vv[16];                                                       \
        _Pragma("unroll")                                                    \
        for (int t = 0; t < 16; t++) {                                       \
            int k = (r) * 16 + t;                                            \
            unsigned s = (k < degc) ? __builtin_amdgcn_readlane(cv, k) : si; \
            vv[t] = __half22float2(hb[(size_t)s * 64u + lane]);              \
        }                                                                    \
        ax += ((vv[0].x + vv[1].x) + (vv[2].x + vv[3].x))                    \
            + ((vv[4].x + vv[5].x) + (vv[6].x + vv[7].x))                    \
            + ((vv[8].x + vv[9].x) + (vv[10].x + vv[11].x))                  \
            + ((vv[12].x + vv[13].x) + (vv[14].x + vv[15].x));               \
        ay += ((vv[0].y + vv[1].y) + (vv[2].y + vv[3].y))                    \
            + ((vv[4].y + vv[5].y) + (vv[6].y + vv[7].y))                    \
            + ((vv[8].y + vv[9].y) + (vv[10].y + vv[11].y))                  \
            + ((vv[12].y + vv[13].y) + (vv[14].y + vv[15].y));               \
    }

    if (degc > 0)  ROUND16(0)
    if (degc > 16) ROUND16(1)
    if (degc > 32) ROUND16(2)
    if (degc > 48) ROUND16(3)
#undef ROUND16

    float di = dinv[si];
    ax *= di;
    ay *= di;

    float2 bv = ((const float2*)b1)[lane];
    float h0 = fmaxf(ax + bv.x, 0.f);
    float h1 = fmaxf(ay + bv.y, 0.f);

    float4 w = ((const float4*)W2)[lane];
    float pz0 = fmaf(h0, w.x, h1 * w.z);
    float pz1 = fmaf(h0, w.y, h1 * w.w);
#pragma unroll
    for (int off = 32; off > 0; off >>= 1) {
        pz0 += __shfl_down(pz0, off);
        pz1 += __shfl_down(pz1, off);
    }
    if (lane == 0) {
        float2* zp = (float2*)(z + (size_t)si * 2);
        *zp = make_float2(pz0 * di, pz1 * di);  // prescale for layer-2 aggregation
    }
}

// Layer-2 aggregation over prescaled z'. 16 lanes per node (avg degree 16):
// 4 nodes/wave, width-16 shuffle reduce. out[i] = (Σ z'[s] + z'[i])*dinv[i] + b2.
__launch_bounds__(256)
__global__ void agg2_k(const float* __restrict__ z, const unsigned* __restrict__ cnt,
                       const unsigned* __restrict__ col, const float* __restrict__ dinv,
                       const float* __restrict__ b2, float* __restrict__ out) {
    int i = (blockIdx.x * 256 + threadIdx.x) >> 4;
    int sl = threadIdx.x & 15;
    if (i >= NN) return;

    unsigned deg = cnt[i];
    if (deg > SLOTS) deg = SLOTS;
    unsigned p0 = (unsigned)i * SLOTS, p1 = p0 + deg;
    float a0 = 0.f, a1 = 0.f;
    for (unsigned e = p0 + sl; e < p1; e += 16) {
        unsigned s = col[e];
        float2 v = ((const float2*)z)[s];
        a0 += v.x;
        a1 += v.y;
    }
#pragma unroll
    for (int off = 8; off > 0; off >>= 1) {
        a0 += __shfl_down(a0, off, 16);
        a1 += __shfl_down(a1, off, 16);
    }
    if (sl == 0) {
        float di = dinv[i];
        float2 zi = ((const float2*)z)[i];
        out[(size_t)i * 2]     = (a0 + zi.x) * di + b2[0];
        out[(size_t)i * 2 + 1] = (a1 + zi.y) * di + b2[1];
    }
}

extern "C" void kernel_launch(void* const* d_in, const int* in_sizes, int n_in,
                              void* d_out, int out_size, void* d_ws, size_t ws_size,
                              hipStream_t stream) {
    const float* x  = (const float*)d_in[0];
    const int*   ei = (const int*)d_in[1];
    const float* W1 = (const float*)d_in[2];
    const float* b1 = (const float*)d_in[3];
    const float* W2 = (const float*)d_in[4];
    const float* b2 = (const float*)d_in[5];
    float* out = (float*)d_out;

    char* ws = (char*)d_ws;
    unsigned* cnt  = (unsigned*)(ws);
    float*    dinv = (float*)(ws + 400000);
    float*    z    = (float*)(ws + 800000);
    _Float16* Wt   = (_Float16*)(ws + 1600000);
    unsigned* col  = (unsigned*)(ws + 1638400);
    _Float16* h    = (_Float16*)(ws + 27238400);

    hipMemsetAsync(cnt, 0, NN * sizeof(unsigned), stream);
    scat_k<<<(NE / 4 + 255) / 256, 256, 0, stream>>>(ei, cnt, col, W1, Wt);
    gemm1_k<<<NBK, 256, 0, stream>>>(x, Wt, cnt, dinv, h);
    agg1_k<<<(NN * 64 + 255) / 256, 256, 0, stream>>>(h, cnt, col, dinv, b1, W2, z);
    agg2_k<<<(NN * 16 + 255) / 256, 256, 0, stream>>>(z, cnt, col, dinv, b2, out);
}

// Round 12
// 226.698 us; speedup vs baseline: 1.4023x; 1.4023x over previous
//
#include <hip/hip_runtime.h>
#include <hip/hip_fp16.h>
#include <cstdint>
#include <cstddef>

#define NN 100000
#define NE 1600000
#define D 128
#define NBK 782            // ceil(NN / 128) buckets of 128 nodes
#define NBLK_P 200         // partition blocks (known-best config, R5)
#define EPB 8000           // edges per partition block (200*8000 = 1.6M exact)
#define CAP 3072           // slots per bucket (mean 2048, +22 sigma; overflow clamped)

typedef _Float16 half8 __attribute__((ext_vector_type(8)));
typedef _Float16 half4v __attribute__((ext_vector_type(4)));
typedef float f32x4 __attribute__((ext_vector_type(4)));

// ---------------- workspace layout (bytes) ----------------
// part  : 782*3072 u32 @ 0         (9,609,216)   read by p4g — h must NOT overlap
// gcnt  : 782*16 u32  @ 9,609,216  (   50,048)   (1 counter/line; memset pre-zeroed)
// z'    : NN*2 f32    @ 25,600,000 (   800,000)
// dinv  : NN f32      @ 26,400,000 (   400,000)
// rp    : NN u32      @ 26,800,000 (   400,000)
// re    : NN u32      @ 27,200,000 (   400,000)
// col   : 782*3072 u32 @ 27,600,000 (9,609,216+256 pad)  bucket-slotted
// Wt    : 128*128 f16 @ 37,300,000 (    32,768)
// h'    : NN*128 f16  @ 40,000,000 (25,600,000)
// R11 lesson: single-pass scatter = 15x write amp (random 4B stores, 64B
// lines). The two-pass sort exists to cluster stores into ~10-slot runs.

// PSCAT: fused histogram + range-reserve + scatter (measured ~27us at 200x256).
__launch_bounds__(256)
__global__ void pscat_k(const int* __restrict__ ei, unsigned* __restrict__ gcnt,
                        unsigned* __restrict__ part,
                        const float* __restrict__ W, _Float16* __restrict__ Wt) {
    __shared__ unsigned hist[NBK];
    __shared__ unsigned run[NBK];
    int tid = threadIdx.x, b = blockIdx.x;
    for (int k = tid; k < NBK; k += 256) hist[k] = 0u;
    __syncthreads();
    int e0 = b * EPB;
    for (int i = tid * 4; i < EPB; i += 1024) {
        int4 d4 = *(const int4*)(ei + NE + e0 + i);
        atomicAdd(&hist[d4.x >> 7], 1u);
        atomicAdd(&hist[d4.y >> 7], 1u);
        atomicAdd(&hist[d4.z >> 7], 1u);
        atomicAdd(&hist[d4.w >> 7], 1u);
    }
    __syncthreads();
    for (int k = tid; k < NBK; k += 256) {
        unsigned c = hist[k];
        run[k] = c ? atomicAdd(&gcnt[k * 16], c) : 0u;
    }
    if (b < 64) {  // fused Wt transpose+cast, overlaps the atomic latency
        int idx = b * 256 + tid;
        int n = idx >> 7, kk = idx & 127;
        Wt[idx] = (_Float16)W[kk * 128 + n];
    }
    __syncthreads();
    for (int i = tid * 4; i < EPB; i += 1024) {
        int4 s4 = *(const int4*)(ei + e0 + i);
        int4 d4 = *(const int4*)(ei + NE + e0 + i);
        unsigned k, slot;
        k = (unsigned)(d4.x >> 7); slot = atomicAdd(&run[k], 1u);
        if (slot < CAP) part[(size_t)k * CAP + slot] = (unsigned)s4.x | ((unsigned)(d4.x & 127) << 20);
        k = (unsigned)(d4.y >> 7); slot = atomicAdd(&run[k], 1u);
        if (slot < CAP) part[(size_t)k * CAP + slot] = (unsigned)s4.y | ((unsigned)(d4.y & 127) << 20);
        k = (unsigned)(d4.z >> 7); slot = atomicAdd(&run[k], 1u);
        if (slot < CAP) part[(size_t)k * CAP + slot] = (unsigned)s4.z | ((unsigned)(d4.z & 127) << 20);
        k = (unsigned)(d4.w >> 7); slot = atomicAdd(&run[k], 1u);
        if (slot < CAP) part[(size_t)k * CAP + slot] = (unsigned)s4.w | ((unsigned)(d4.w & 127) << 20);
    }
}

// P4G: fused CSR-build + GEMM (R9, measured-good). One block per 128-node
// bucket; p4 scratch aliased into xs; gemm epilogue reads dinv from LDS.
__launch_bounds__(256)
__global__ void p4g_k(const unsigned* __restrict__ part, const unsigned* __restrict__ gcnt,
                      const float* __restrict__ x, const _Float16* __restrict__ Wt,
                      unsigned* __restrict__ rp, unsigned* __restrict__ re,
                      float* __restrict__ dinv, unsigned* __restrict__ col,
                      _Float16* __restrict__ h) {
    __shared__ __align__(16) _Float16 wt[128 * 136];
    __shared__ __align__(16) _Float16 xs[128 * 72];
    __shared__ float dinvs[128];
    unsigned* cc  = (unsigned*)xs;
    unsigned* pp  = cc + 128;
    unsigned* run = pp + 128;
    int tid = threadIdx.x, k = blockIdx.x;
    int n0 = k << 7;
    int nodes = (NN - n0 < 128) ? (NN - n0) : 128;
    int w = tid >> 6, lane = tid & 63;
    int m = lane & 15, q4 = lane >> 4;

#pragma unroll
    for (int q = 0; q < 8; q++) {
        int idx = q * 256 + tid;
        int n = idx >> 4, k8 = (idx & 15) * 8;
        *(half8*)(&wt[n * 136 + k8]) = *(const half8*)(Wt + n * 128 + k8);
    }

    unsigned cnt = gcnt[k * 16];
    if (cnt > CAP) cnt = CAP;
    unsigned e0c = (unsigned)k * CAP;
    const unsigned* pk = part + (size_t)k * CAP;

    if (tid < 128) cc[tid] = 0u;
    __syncthreads();
    for (unsigned t = tid; t < cnt; t += 256)
        atomicAdd(&cc[(pk[t] >> 20) & 127], 1u);
    __syncthreads();

    unsigned myc = (tid < 128) ? cc[tid] : 0u;
    if (tid < 128) pp[tid] = myc;
    __syncthreads();
    for (int off = 1; off < 128; off <<= 1) {
        unsigned u = 0;
        if (tid < 128 && tid >= off) u = pp[tid - off];
        __syncthreads();
        if (tid < 128) pp[tid] += u;
        __syncthreads();
    }
    if (tid < 128) {
        unsigned excl = pp[tid] - myc;
        run[tid] = excl;
        float dv = rsqrtf((float)(myc + 1u));
        dinvs[tid] = dv;
        if (tid < nodes) {
            rp[n0 + tid] = e0c + excl;
            re[n0 + tid] = e0c + excl + myc;
            dinv[n0 + tid] = dv;
        }
    }
    __syncthreads();

    for (unsigned t = tid; t < cnt; t += 256) {
        unsigned v = pk[t];
        unsigned dlo = (v >> 20) & 127;
        unsigned pos = e0c + atomicAdd(&run[dlo], 1u);
        col[pos] = v & 0xFFFFFu;
    }
    __syncthreads();  // run (aliased in xs) fully consumed before xs staging

    f32x4 acc[2][8];
#pragma unroll
    for (int rt = 0; rt < 2; rt++)
#pragma unroll
        for (int nt = 0; nt < 8; nt++) acc[rt][nt] = (f32x4){0.f, 0.f, 0.f, 0.f};

    for (int ks = 0; ks <= 64; ks += 64) {
        if (ks) __syncthreads();
#pragma unroll
        for (int q = 0; q < 8; q++) {
            int idx = q * 256 + tid;
            int row = idx >> 4;
            int c4 = (idx & 15) * 4;
            int gr = n0 + row;
            float4 v = (gr < NN) ? *(const float4*)(x + (size_t)gr * 128 + ks + c4)
                                 : make_float4(0, 0, 0, 0);
            half4v hv = { (_Float16)v.x, (_Float16)v.y, (_Float16)v.z, (_Float16)v.w };
            *(half4v*)(&xs[row * 72 + c4]) = hv;
        }
        __syncthreads();

#pragma unroll
        for (int kc = 0; kc < 2; kc++) {
            half8 a0 = *(const half8*)(&xs[(w * 32 + m) * 72 + kc * 32 + q4 * 8]);
            half8 a1 = *(const half8*)(&xs[(w * 32 + 16 + m) * 72 + kc * 32 + q4 * 8]);
#pragma unroll
            for (int nt = 0; nt < 8; nt++) {
                half8 bf = *(const half8*)(&wt[(nt * 16 + m) * 136 + ks + kc * 32 + q4 * 8]);
                acc[0][nt] = __builtin_amdgcn_mfma_f32_16x16x32_f16(a0, bf, acc[0][nt], 0, 0, 0);
                acc[1][nt] = __builtin_amdgcn_mfma_f32_16x16x32_f16(a1, bf, acc[1][nt], 0, 0, 0);
            }
        }
    }

    float dv[2][4];
#pragma unroll
    for (int rt = 0; rt < 2; rt++)
#pragma unroll
        for (int r = 0; r < 4; r++)
            dv[rt][r] = dinvs[w * 32 + rt * 16 + q4 * 4 + r];
    __syncthreads();
#pragma unroll
    for (int rt = 0; rt < 2; rt++)
#pragma unroll
        for (int nt = 0; nt < 8; nt++)
#pragma unroll
            for (int r = 0; r < 4; r++)
                wt[(w * 32 + rt * 16 + q4 * 4 + r) * 136 + nt * 16 + m] =
                    (_Float16)(acc[rt][nt][r] * dv[rt][r]);
    __syncthreads();
#pragma unroll
    for (int q = 0; q < 8; q++) {
        int idx = q * 256 + tid;
        int row = idx >> 4;
        int c8 = (idx & 15) * 8;
        int gr = n0 + row;
        if (gr < NN)
            *(half8*)(h + (size_t)gr * 128 + c8) = *(const half8*)(&wt[row * 136 + c8]);
    }
}

// Layer-1 aggregation body (R9 roofline structure), node range [nb, ne).
// MEASUREMENT ROUND: instantiated as two uniquely-named kernels so both
// halves AND the remaining kernels all surface in the top-5 table.
__device__ __forceinline__ void agg1_body(
        const _Float16* __restrict__ h, const unsigned* __restrict__ rp,
        const unsigned* __restrict__ re, const unsigned* __restrict__ col,
        const float* __restrict__ dinv, const float* __restrict__ b1,
        const float* __restrict__ W2, float* __restrict__ z, int nb, int ne) {
    int i = nb + ((blockIdx.x * 256 + threadIdx.x) >> 6);
    int lane = threadIdx.x & 63;
    if (i >= ne) return;
    unsigned si = __builtin_amdgcn_readfirstlane((unsigned)i);

    const __half2* hb = (const __half2*)h;
    unsigned p0 = __builtin_amdgcn_readfirstlane(rp[si]);
    unsigned p1 = __builtin_amdgcn_readfirstlane(re[si]);
    int deg = (int)(p1 - p0);

    unsigned cv = col[p0 + (unsigned)lane];

    int degc = deg > 64 ? 64 : deg;
    int R = (degc + 15) >> 4;
    float2 sv = __half22float2(hb[(size_t)si * 64u + lane]);
    float f = (float)(1 + degc - 16 * R);
    float ax = f * sv.x, ay = f * sv.y;

#define ROUND16(r)                                                           \
    {                                                                        \
        float2 vv[16];                                                       \
        _Pragma("unroll")                                                    \
        for (int t = 0; t < 16; t++) {                                       \
            int k = (r) * 16 + t;                                            \
            unsigned s = (k < degc) ? __builtin_amdgcn_readlane(cv, k) : si; \
            vv[t] = __half22float2(hb[(size_t)s * 64u + lane]);              \
        }                                                                    \
        ax += ((vv[0].x + vv[1].x) + (vv[2].x + vv[3].x))                    \
            + ((vv[4].x + vv[5].x) + (vv[6].x + vv[7].x))                    \
            + ((vv[8].x + vv[9].x) + (vv[10].x + vv[11].x))                  \
            + ((vv[12].x + vv[13].x) + (vv[14].x + vv[15].x));               \
        ay += ((vv[0].y + vv[1].y) + (vv[2].y + vv[3].y))                    \
            + ((vv[4].y + vv[5].y) + (vv[6].y + vv[7].y))                    \
            + ((vv[8].y + vv[9].y) + (vv[10].y + vv[11].y))                  \
            + ((vv[12].y + vv[13].y) + (vv[14].y + vv[15].y));               \
    }

    if (degc > 0)  ROUND16(0)
    if (degc > 16) ROUND16(1)
    if (degc > 32) ROUND16(2)
    if (degc > 48) ROUND16(3)
#undef ROUND16

    for (unsigned e = p0 + 64; e < p1; ++e) {
        unsigned s_ = __builtin_amdgcn_readfirstlane(col[e]);
        float2 v = __half22float2(hb[(size_t)s_ * 64u + lane]);
        ax += v.x;
        ay += v.y;
    }

    float di = dinv[si];
    ax *= di;
    ay *= di;

    float2 bv = ((const float2*)b1)[lane];
    float h0 = fmaxf(ax + bv.x, 0.f);
    float h1 = fmaxf(ay + bv.y, 0.f);

    float4 w = ((const float4*)W2)[lane];
    float pz0 = fmaf(h0, w.x, h1 * w.z);
    float pz1 = fmaf(h0, w.y, h1 * w.w);
#pragma unroll
    for (int off = 32; off > 0; off >>= 1) {
        pz0 += __shfl_down(pz0, off);
        pz1 += __shfl_down(pz1, off);
    }
    if (lane == 0) {
        float2* zp = (float2*)(z + (size_t)si * 2);
        *zp = make_float2(pz0 * di, pz1 * di);
    }
}

__launch_bounds__(256)
__global__ void agg1a_k(const _Float16* __restrict__ h, const unsigned* __restrict__ rp,
                        const unsigned* __restrict__ re, const unsigned* __restrict__ col,
                        const float* __restrict__ dinv, const float* __restrict__ b1,
                        const float* __restrict__ W2, float* __restrict__ z) {
    agg1_body(h, rp, re, col, dinv, b1, W2, z, 0, 50000);
}

__launch_bounds__(256)
__global__ void agg1b_k(const _Float16* __restrict__ h, const unsigned* __restrict__ rp,
                        const unsigned* __restrict__ re, const unsigned* __restrict__ col,
                        const float* __restrict__ dinv, const float* __restrict__ b1,
                        const float* __restrict__ W2, float* __restrict__ z) {
    agg1_body(h, rp, re, col, dinv, b1, W2, z, 50000, NN);
}

// Layer-2 aggregation over prescaled z'.
__launch_bounds__(256)
__global__ void agg2_k(const float* __restrict__ z, const unsigned* __restrict__ rp,
                       const unsigned* __restrict__ re, const unsigned* __restrict__ col,
                       const float* __restrict__ dinv, const float* __restrict__ b2,
                       float* __restrict__ out) {
    int i = (blockIdx.x * 256 + threadIdx.x) >> 4;
    int sl = threadIdx.x & 15;
    if (i >= NN) return;

    unsigned p0 = rp[i], p1 = re[i];
    float a0 = 0.f, a1 = 0.f;
    for (unsigned e = p0 + sl; e < p1; e += 16) {
        unsigned s = col[e];
        float2 v = ((const float2*)z)[s];
        a0 += v.x;
        a1 += v.y;
    }
#pragma unroll
    for (int off = 8; off > 0; off >>= 1) {
        a0 += __shfl_down(a0, off, 16);
        a1 += __shfl_down(a1, off, 16);
    }
    if (sl == 0) {
        float di = dinv[i];
        float2 zi = ((const float2*)z)[i];
        out[(size_t)i * 2]     = (a0 + zi.x) * di + b2[0];
        out[(size_t)i * 2 + 1] = (a1 + zi.y) * di + b2[1];
    }
}

extern "C" void kernel_launch(void* const* d_in, const int* in_sizes, int n_in,
                              void* d_out, int out_size, void* d_ws, size_t ws_size,
                              hipStream_t stream) {
    const float* x  = (const float*)d_in[0];
    const int*   ei = (const int*)d_in[1];
    const float* W1 = (const float*)d_in[2];
    const float* b1 = (const float*)d_in[3];
    const float* W2 = (const float*)d_in[4];
    const float* b2 = (const float*)d_in[5];
    float* out = (float*)d_out;

    char* ws = (char*)d_ws;
    unsigned* part = (unsigned*)(ws);
    unsigned* gcnt = (unsigned*)(ws + 9609216);
    float*    z    = (float*)(ws + 25600000);
    float*    dinv = (float*)(ws + 26400000);
    unsigned* rp   = (unsigned*)(ws + 26800000);
    unsigned* re   = (unsigned*)(ws + 27200000);
    unsigned* col  = (unsigned*)(ws + 27600000);
    _Float16* Wt   = (_Float16*)(ws + 37300000);
    _Float16* h    = (_Float16*)(ws + 40000000);

    hipMemsetAsync(gcnt, 0, 782 * 16 * sizeof(unsigned), stream);
    pscat_k<<<NBLK_P, 256, 0, stream>>>(ei, gcnt, part, W1, Wt);
    p4g_k<<<NBK, 256, 0, stream>>>(part, gcnt, x, Wt, rp, re, dinv, col, h);
    agg1a_k<<<(50000 * 64 + 255) / 256, 256, 0, stream>>>(h, rp, re, col, dinv, b1, W2, z);
    agg1b_k<<<(50000 * 64 + 255) / 256, 256, 0, stream>>>(h, rp, re, col, dinv, b1, W2, z);
    agg2_k<<<(NN * 16 + 255) / 256, 256, 0, stream>>>(z, rp, re, col, dinv, b2, out);
}

// Round 13
// 212.296 us; speedup vs baseline: 1.4974x; 1.0678x over previous
//
#include <hip/hip_runtime.h>
#include <hip/hip_fp16.h>
#include <cstdint>
#include <cstddef>

#define NN 100000
#define NE 1600000
#define D 128
#define NBK 782            // ceil(NN / 128) buckets of 128 nodes
#define NBLK_P 200         // partition blocks (known-best config, R5)
#define EPB 8000           // edges per partition block (200*8000 = 1.6M exact)
#define CAP 3072           // slots per bucket (mean 2048, +22 sigma; overflow clamped)

typedef _Float16 half8 __attribute__((ext_vector_type(8)));
typedef float f32x4 __attribute__((ext_vector_type(4)));

// ---------------- workspace layout (bytes) ----------------
// part  : 782*3072 u32 @ 0         (9,609,216)   read by p4g — h must NOT overlap
// gcnt  : 782*16 u32  @ 9,609,216  (   50,048)   (1 counter/line; memset pre-zeroed)
// z'    : NN*2 f32    @ 25,600,000 (   800,000)
// dinv  : NN f32      @ 26,400,000 (   400,000)
// rp    : NN u32      @ 26,800,000 (   400,000)
// re    : NN u32      @ 27,200,000 (   400,000)
// col   : 782*3072 u32 @ 27,600,000 (9,609,216+256 pad)  bucket-slotted
// Wt    : 128*128 f16 @ 37,300,000 (    32,768)
// h'    : NN*128 f16  @ 40,000,000 (25,600,000)
// R11 lesson: single-pass scatter = 15x write amp. R12 measurement: p4g was
// 48us at 13% occupancy — single-block latency chain (19 barriers, 3 blk/CU).

// PSCAT: fused histogram + range-reserve + scatter (measured ~27us at 200x256).
__launch_bounds__(256)
__global__ void pscat_k(const int* __restrict__ ei, unsigned* __restrict__ gcnt,
                        unsigned* __restrict__ part,
                        const float* __restrict__ W, _Float16* __restrict__ Wt) {
    __shared__ unsigned hist[NBK];
    __shared__ unsigned run[NBK];
    int tid = threadIdx.x, b = blockIdx.x;
    for (int k = tid; k < NBK; k += 256) hist[k] = 0u;
    __syncthreads();
    int e0 = b * EPB;
    for (int i = tid * 4; i < EPB; i += 1024) {
        int4 d4 = *(const int4*)(ei + NE + e0 + i);
        atomicAdd(&hist[d4.x >> 7], 1u);
        atomicAdd(&hist[d4.y >> 7], 1u);
        atomicAdd(&hist[d4.z >> 7], 1u);
        atomicAdd(&hist[d4.w >> 7], 1u);
    }
    __syncthreads();
    for (int k = tid; k < NBK; k += 256) {
        unsigned c = hist[k];
        run[k] = c ? atomicAdd(&gcnt[k * 16], c) : 0u;
    }
    if (b < 64) {  // fused Wt transpose+cast, overlaps the atomic latency
        int idx = b * 256 + tid;
        int n = idx >> 7, kk = idx & 127;
        Wt[idx] = (_Float16)W[kk * 128 + n];
    }
    __syncthreads();
    for (int i = tid * 4; i < EPB; i += 1024) {
        int4 s4 = *(const int4*)(ei + e0 + i);
        int4 d4 = *(const int4*)(ei + NE + e0 + i);
        unsigned k, slot;
        k = (unsigned)(d4.x >> 7); slot = atomicAdd(&run[k], 1u);
        if (slot < CAP) part[(size_t)k * CAP + slot] = (unsigned)s4.x | ((unsigned)(d4.x & 127) << 20);
        k = (unsigned)(d4.y >> 7); slot = atomicAdd(&run[k], 1u);
        if (slot < CAP) part[(size_t)k * CAP + slot] = (unsigned)s4.y | ((unsigned)(d4.y & 127) << 20);
        k = (unsigned)(d4.z >> 7); slot = atomicAdd(&run[k], 1u);
        if (slot < CAP) part[(size_t)k * CAP + slot] = (unsigned)s4.z | ((unsigned)(d4.z & 127) << 20);
        k = (unsigned)(d4.w >> 7); slot = atomicAdd(&run[k], 1u);
        if (slot < CAP) part[(size_t)k * CAP + slot] = (unsigned)s4.w | ((unsigned)(d4.w & 127) << 20);
    }
}

// P4G v2: fused CSR-build + GEMM, de-serialized (R12 diagnosis: 48us at 13%
// occupancy = single-block latency chain). Changes vs R9:
//  - NO xs staging: A-fragments load directly from global x (each lane reads
//    its own 32B row-chunk; lines fully consumed; each x element read once)
//    -> removes 18.4KB LDS + 3 barriers + fp32->fp16 LDS round-trip.
//  - wave-0 shfl scan (2 elems/lane, no inner barriers) replaces the
//    14-barrier 128-wide LDS scan.
//  - LDS 36.4KB -> 4 blocks/CU (launch_bounds(256,4)); barriers 19 -> 5.
// Verified MFMA layouts: A[m=lane&15][k=(lane>>4)*8+j], B[k][n=lane&15],
//                        C/D col=lane&15 row=(lane>>4)*4+reg.
__launch_bounds__(256, 4)
__global__ void p4g_k(const unsigned* __restrict__ part, const unsigned* __restrict__ gcnt,
                      const float* __restrict__ x, const _Float16* __restrict__ Wt,
                      unsigned* __restrict__ rp, unsigned* __restrict__ re,
                      float* __restrict__ dinv, unsigned* __restrict__ col,
                      _Float16* __restrict__ h) {
    __shared__ __align__(16) _Float16 wt[128 * 136];  // B: wt[n][k]; reused as epilogue buffer
    __shared__ unsigned cc[128];    // per-node counts
    __shared__ unsigned run[128];   // scatter cursors
    __shared__ float dinvs[128];
    int tid = threadIdx.x, k = blockIdx.x;
    int n0 = k << 7;
    int w = tid >> 6, lane = tid & 63;
    int m = lane & 15, q4 = lane >> 4;

    // stage Wt: 2048 half8 chunks, coalesced global, conflict-free LDS
#pragma unroll
    for (int q = 0; q < 8; q++) {
        int idx = q * 256 + tid;
        int n = idx >> 4, k8 = (idx & 15) * 8;
        *(half8*)(&wt[n * 136 + k8]) = *(const half8*)(Wt + n * 128 + k8);
    }

    unsigned cnt = gcnt[k * 16];
    if (cnt > CAP) cnt = CAP;
    unsigned e0c = (unsigned)k * CAP;
    const unsigned* pk = part + (size_t)k * CAP;

    if (tid < 128) cc[tid] = 0u;
    __syncthreads();                                   // [b1]
    for (unsigned t = tid; t < cnt; t += 256)
        atomicAdd(&cc[(pk[t] >> 20) & 127], 1u);
    __syncthreads();                                   // [b2]

    // wave-0 shfl scan over 128 counters (2/lane), zero inner barriers
    if (tid < 64) {
        unsigned c0 = cc[tid], c1 = cc[64 + tid];
        unsigned v0 = c0, v1 = c1;
#pragma unroll
        for (int off = 1; off < 64; off <<= 1) {
            unsigned u = __shfl_up(v0, off);
            if (tid >= off) v0 += u;
        }
#pragma unroll
        for (int off = 1; off < 64; off <<= 1) {
            unsigned u = __shfl_up(v1, off);
            if (tid >= off) v1 += u;
        }
        v1 += __shfl(v0, 63);                // carry total of first half
        unsigned ex0 = v0 - c0, ex1 = v1 - c1;
        run[tid] = ex0;
        run[64 + tid] = ex1;
        float dv0 = rsqrtf((float)(c0 + 1u));
        float dv1 = rsqrtf((float)(c1 + 1u));
        dinvs[tid] = dv0;
        dinvs[64 + tid] = dv1;
        int g0 = n0 + tid, g1 = n0 + 64 + tid;
        if (g0 < NN) { rp[g0] = e0c + ex0; re[g0] = e0c + ex0 + c0; dinv[g0] = dv0; }
        if (g1 < NN) { rp[g1] = e0c + ex1; re[g1] = e0c + ex1 + c1; dinv[g1] = dv1; }
    }
    __syncthreads();                                   // [b3]

    for (unsigned t = tid; t < cnt; t += 256) {
        unsigned v = pk[t];
        unsigned dlo = (v >> 20) & 127;
        unsigned pos = e0c + atomicAdd(&run[dlo], 1u);
        col[pos] = v & 0xFFFFFu;
    }
    // no barrier: gemm below touches only wt (staged pre-b1) and x/registers

    // gemm: 4 waves, wave w owns rows w*32..w*32+31; A-frags direct from x.
    int r0 = n0 + w * 32 + m;
    int r1 = r0 + 16;
    bool ok0 = r0 < NN, ok1 = r1 < NN;
    const float* xr0 = x + (size_t)r0 * 128 + q4 * 8;
    const float* xr1 = x + (size_t)r1 * 128 + q4 * 8;

    f32x4 acc[2][8];
#pragma unroll
    for (int rt = 0; rt < 2; rt++)
#pragma unroll
        for (int nt = 0; nt < 8; nt++) acc[rt][nt] = (f32x4){0.f, 0.f, 0.f, 0.f};

#pragma unroll
    for (int ks = 0; ks < 128; ks += 32) {
        float4 f00 = ok0 ? *(const float4*)(xr0 + ks)     : make_float4(0, 0, 0, 0);
        float4 f01 = ok0 ? *(const float4*)(xr0 + ks + 4) : make_float4(0, 0, 0, 0);
        float4 f10 = ok1 ? *(const float4*)(xr1 + ks)     : make_float4(0, 0, 0, 0);
        float4 f11 = ok1 ? *(const float4*)(xr1 + ks + 4) : make_float4(0, 0, 0, 0);
        half8 a0 = { (_Float16)f00.x, (_Float16)f00.y, (_Float16)f00.z, (_Float16)f00.w,
                     (_Float16)f01.x, (_Float16)f01.y, (_Float16)f01.z, (_Float16)f01.w };
        half8 a1 = { (_Float16)f10.x, (_Float16)f10.y, (_Float16)f10.z, (_Float16)f10.w,
                     (_Float16)f11.x, (_Float16)f11.y, (_Float16)f11.z, (_Float16)f11.w };
#pragma unroll
        for (int nt = 0; nt < 8; nt++) {
            half8 bf = *(const half8*)(&wt[(nt * 16 + m) * 136 + ks + q4 * 8]);
            acc[0][nt] = __builtin_amdgcn_mfma_f32_16x16x32_f16(a0, bf, acc[0][nt], 0, 0, 0);
            acc[1][nt] = __builtin_amdgcn_mfma_f32_16x16x32_f16(a1, bf, acc[1][nt], 0, 0, 0);
        }
    }

    // epilogue: scale by dinv (LDS), fp16, stage in wt (dead), coalesced store
    float dv[2][4];
#pragma unroll
    for (int rt = 0; rt < 2; rt++)
#pragma unroll
        for (int r = 0; r < 4; r++)
            dv[rt][r] = dinvs[w * 32 + rt * 16 + q4 * 4 + r];
    __syncthreads();                                   // [b4] wt reads + scatter done
#pragma unroll
    for (int rt = 0; rt < 2; rt++)
#pragma unroll
        for (int nt = 0; nt < 8; nt++)
#pragma unroll
            for (int r = 0; r < 4; r++)
                wt[(w * 32 + rt * 16 + q4 * 4 + r) * 136 + nt * 16 + m] =
                    (_Float16)(acc[rt][nt][r] * dv[rt][r]);
    __syncthreads();                                   // [b5]
#pragma unroll
    for (int q = 0; q < 8; q++) {
        int idx = q * 256 + tid;
        int row = idx >> 4;
        int c8 = (idx & 15) * 8;
        int gr = n0 + row;
        if (gr < NN)
            *(half8*)(h + (size_t)gr * 128 + c8) = *(const half8*)(&wt[row * 136 + c8]);
    }
}

// Layer-1 aggregation of prescaled h' + bias/ReLU + 128x2 W2 projection.
// One wave per node; lane holds half2 (4B chunk; 64 lanes = full 256B row).
// Measured at the fill-path roofline (58.9us vs 193MB/3.37TB/s = 57us).
__launch_bounds__(256)
__global__ void agg1_k(const _Float16* __restrict__ h, const unsigned* __restrict__ rp,
                       const unsigned* __restrict__ re, const unsigned* __restrict__ col,
                       const float* __restrict__ dinv, const float* __restrict__ b1,
                       const float* __restrict__ W2, float* __restrict__ z) {
    int i = (blockIdx.x * 256 + threadIdx.x) >> 6;
    int lane = threadIdx.x & 63;
    if (i >= NN) return;
    unsigned si = __builtin_amdgcn_readfirstlane((unsigned)i);  // force SGPR

    const __half2* hb = (const __half2*)h;
    unsigned p0 = __builtin_amdgcn_readfirstlane(rp[si]);
    unsigned p1 = __builtin_amdgcn_readfirstlane(re[si]);
    int deg = (int)(p1 - p0);

    // col window: one per-lane load covers up to 64 edge ids. May read past p1
    // (stays inside the padded slotted col); unused lanes masked by (k<degc).
    unsigned cv = col[p0 + (unsigned)lane];

    int degc = deg > 64 ? 64 : deg;
    int R = (degc + 15) >> 4;                 // full 16-rounds incl. padding
    float2 sv = __half22float2(hb[(size_t)si * 64u + lane]);
    float f = (float)(1 + degc - 16 * R);     // corrects padding reads of row si
    float ax = f * sv.x, ay = f * sv.y;

#define ROUND16(r)                                                           \
    {                                                                        \
        float2 vv[16];                                                       \
        _Pragma("unroll")                                                    \
        for (int t = 0; t < 16; t++) {                                       \
            int k = (r) * 16 + t;                                            \
            unsigned s = (k < degc) ? __builtin_amdgcn_readlane(cv, k) : si; \
            vv[t] = __half22float2(hb[(size_t)s * 64u + lane]);              \
        }                                                                    \
        ax += ((vv[0].x + vv[1].x) + (vv[2].x + vv[3].x))                    \
            + ((vv[4].x + vv[5].x) + (vv[6].x + vv[7].x))                    \
            + ((vv[8].x + vv[9].x) + (vv[10].x + vv[11].x))                  \
            + ((vv[12].x + vv[13].x) + (vv[14].x + vv[15].x));               \
        ay += ((vv[0].y + vv[1].y) + (vv[2].y + vv[3].y))                    \
            + ((vv[4].y + vv[5].y) + (vv[6].y + vv[7].y))                    \
            + ((vv[8].y + vv[9].y) + (vv[10].y + vv[11].y))                  \
            + ((vv[12].y + vv[13].y) + (vv[14].y + vv[15].y));               \
    }

    if (degc > 0)  ROUND16(0)
    if (degc > 16) ROUND16(1)
    if (degc > 32) ROUND16(2)
    if (degc > 48) ROUND16(3)
#undef ROUND16

    // deg > 64 remainder (Poisson(16): essentially never taken)
    for (unsigned e = p0 + 64; e < p1; ++e) {
        unsigned s_ = __builtin_amdgcn_readfirstlane(col[e]);
        float2 v = __half22float2(hb[(size_t)s_ * 64u + lane]);
        ax += v.x;
        ay += v.y;
    }

    float di = dinv[si];
    ax *= di;
    ay *= di;

    float2 bv = ((const float2*)b1)[lane];
    float h0 = fmaxf(ax + bv.x, 0.f);
    float h1 = fmaxf(ay + bv.y, 0.f);

    float4 w = ((const float4*)W2)[lane];
    float pz0 = fmaf(h0, w.x, h1 * w.z);
    float pz1 = fmaf(h0, w.y, h1 * w.w);
#pragma unroll
    for (int off = 32; off > 0; off >>= 1) {
        pz0 += __shfl_down(pz0, off);
        pz1 += __shfl_down(pz1, off);
    }
    if (lane == 0) {
        float2* zp = (float2*)(z + (size_t)si * 2);
        *zp = make_float2(pz0 * di, pz1 * di);  // prescale for layer-2 aggregation
    }
}

// Layer-2 aggregation over prescaled z'. 16 lanes per node (avg degree 16):
// 4 nodes/wave, width-16 shuffle reduce. out[i] = (Σ z'[s] + z'[i])*dinv[i] + b2.
__launch_bounds__(256)
__global__ void agg2_k(const float* __restrict__ z, const unsigned* __restrict__ rp,
                       const unsigned* __restrict__ re, const unsigned* __restrict__ col,
                       const float* __restrict__ dinv, const float* __restrict__ b2,
                       float* __restrict__ out) {
    int i = (blockIdx.x * 256 + threadIdx.x) >> 4;
    int sl = threadIdx.x & 15;
    if (i >= NN) return;

    unsigned p0 = rp[i], p1 = re[i];
    float a0 = 0.f, a1 = 0.f;
    for (unsigned e = p0 + sl; e < p1; e += 16) {
        unsigned s = col[e];
        float2 v = ((const float2*)z)[s];
        a0 += v.x;
        a1 += v.y;
    }
#pragma unroll
    for (int off = 8; off > 0; off >>= 1) {
        a0 += __shfl_down(a0, off, 16);
        a1 += __shfl_down(a1, off, 16);
    }
    if (sl == 0) {
        float di = dinv[i];
        float2 zi = ((const float2*)z)[i];
        out[(size_t)i * 2]     = (a0 + zi.x) * di + b2[0];
        out[(size_t)i * 2 + 1] = (a1 + zi.y) * di + b2[1];
    }
}

extern "C" void kernel_launch(void* const* d_in, const int* in_sizes, int n_in,
                              void* d_out, int out_size, void* d_ws, size_t ws_size,
                              hipStream_t stream) {
    const float* x  = (const float*)d_in[0];
    const int*   ei = (const int*)d_in[1];
    const float* W1 = (const float*)d_in[2];
    const float* b1 = (const float*)d_in[3];
    const float* W2 = (const float*)d_in[4];
    const float* b2 = (const float*)d_in[5];
    float* out = (float*)d_out;

    char* ws = (char*)d_ws;
    unsigned* part = (unsigned*)(ws);
    unsigned* gcnt = (unsigned*)(ws + 9609216);
    float*    z    = (float*)(ws + 25600000);
    float*    dinv = (float*)(ws + 26400000);
    unsigned* rp   = (unsigned*)(ws + 26800000);
    unsigned* re   = (unsigned*)(ws + 27200000);
    unsigned* col  = (unsigned*)(ws + 27600000);
    _Float16* Wt   = (_Float16*)(ws + 37300000);
    _Float16* h    = (_Float16*)(ws + 40000000);

    hipMemsetAsync(gcnt, 0, 782 * 16 * sizeof(unsigned), stream);
    pscat_k<<<NBLK_P, 256, 0, stream>>>(ei, gcnt, part, W1, Wt);
    p4g_k<<<NBK, 256, 0, stream>>>(part, gcnt, x, Wt, rp, re, dinv, col, h);
    agg1_k<<<(NN * 64 + 255) / 256, 256, 0, stream>>>(h, rp, re, col, dinv, b1, W2, z);
    agg2_k<<<(NN * 16 + 255) / 256, 256, 0, stream>>>(z, rp, re, col, dinv, b2, out);
}